// Round 17
// baseline (204.886 us; speedup 1.0000x reference)
//
#include <hip/hip_runtime.h>
#include <hip/hip_bf16.h>

typedef _Float16 f16;
typedef f16 f16x2 __attribute__((ext_vector_type(2)));
typedef f16 f16x4 __attribute__((ext_vector_type(4)));
typedef f16 f16x8 __attribute__((ext_vector_type(8)));
typedef float f32x2 __attribute__((ext_vector_type(2)));
typedef float f32x4 __attribute__((ext_vector_type(4)));

#define MFMA16(a, b, c) __builtin_amdgcn_mfma_f32_16x16x32_f16(a, b, c, 0, 0, 0)

__device__ __forceinline__ void glds16(const void* g, void* l) {
    __builtin_amdgcn_global_load_lds(
        (const __attribute__((address_space(1))) unsigned int*)g,
        (__attribute__((address_space(3))) unsigned int*)l, 16, 0, 0);
}

#define VM8 asm volatile("s_waitcnt vmcnt(8)" ::: "memory")
#define VM6 asm volatile("s_waitcnt vmcnt(6)" ::: "memory")
#define VM4 asm volatile("s_waitcnt vmcnt(4)" ::: "memory")
#define VM0 asm volatile("s_waitcnt vmcnt(0)" ::: "memory")
#define VMN do {} while (0)
#define SB0 __builtin_amdgcn_sched_barrier(0)

// ---------------- f32 -> f16 convert ----------------
__global__ __launch_bounds__(256) void cvt_kernel(const float* __restrict__ s,
                                                  f16* __restrict__ d, int n) {
    int i = (blockIdx.x * 256 + threadIdx.x) * 8;
    if (i >= n) return;
    float4 a = *(const float4*)(s + i);
    float4 b = *(const float4*)(s + i + 4);
    f16x8 h;
    h[0] = (f16)a.x; h[1] = (f16)a.y; h[2] = (f16)a.z; h[3] = (f16)a.w;
    h[4] = (f16)b.x; h[5] = (f16)b.y; h[6] = (f16)b.z; h[7] = (f16)b.w;
    *(f16x8*)(d + i) = h;
}

// ============ GEMM 128x128 8-phase (mechanical 1/2-scale of proven 256²) ====
// 4 waves (wm=w>>1, wn=w&1); quadrant (MH,NH) 64x64; wave owns 32x32 per
// quadrant (mt,nt in [0,2)). Slabs Ad[buf][MH], Bd[buf][NH] 64x64 f16 = 8KB;
// LDS 64KB -> 2 blocks/CU resident, grid 1024 = 4 serial blocks/CU (overlap
// of prologue/epilogue/fence stalls across blocks — the 256² kernel's gap).
// Fence/stage-slot schedule VERBATIM from the verified 256² kernel (stage
// unit = 2 glds/thread, unchanged counts). NEW: B-fragment persistence —
// bfp[NH] loaded at MH0 phases, reused at MH1 (B LDS amp 4->2).
// COLSUM (gemm1): per-128-row-block column sums; router sums row pairs.
template <int MH, int NH, bool LOADA, bool LOADB>
__device__ __forceinline__ void phase_rw(const f16* Aslab, const f16* Bslab,
                                         f16x8 (&af)[2][2], f16x8 (&bfp)[2][2][2],
                                         int cl, int q, int wm, int wn) {
    if (LOADA) {
#pragma unroll
        for (int mt = 0; mt < 2; ++mt)
#pragma unroll
            for (int ks = 0; ks < 2; ++ks)
                af[mt][ks] =
                    *(const f16x8*)&Aslab[(wm * 32 + mt * 16 + cl) * 64 +
                                          ((ks * 4 + q) ^ (cl & 7)) * 8];
    }
    if (LOADB) {
#pragma unroll
        for (int nt = 0; nt < 2; ++nt)
#pragma unroll
            for (int ks = 0; ks < 2; ++ks)
                bfp[NH][nt][ks] =
                    *(const f16x8*)&Bslab[(wn * 32 + nt * 16 + cl) * 64 +
                                          ((ks * 4 + q) ^ (cl & 7)) * 8];
    }
}

template <int MH, int NH>
__device__ __forceinline__ void phase_mm(f16x8 (&af)[2][2], f16x8 (&bfp)[2][2][2],
                                         f32x4 (&acc)[4][4]) {
    __builtin_amdgcn_s_setprio(1);
#pragma unroll
    for (int mt = 0; mt < 2; ++mt)
#pragma unroll
        for (int nt = 0; nt < 2; ++nt)
#pragma unroll
            for (int ks = 0; ks < 2; ++ks)
                acc[MH * 2 + mt][NH * 2 + nt] =
                    MFMA16(af[mt][ks], bfp[NH][nt][ks], acc[MH * 2 + mt][NH * 2 + nt]);
    __builtin_amdgcn_s_setprio(0);
}

// stage one 64x64 slab (8KB): 2 glds/thread at 256 thr; source pre-swizzled
__device__ __forceinline__ void stage_slab(const f16* gsrc, int ldk, f16* ldst,
                                           int tid) {
#pragma unroll
    for (int j = 0; j < 2; ++j) {
        int idx = j * 256 + tid;
        int rr = idx >> 3;
        int gs = (idx & 7) ^ (rr & 7);
        glds16(gsrc + (size_t)rr * ldk + gs * 8, ldst + (idx & ~63) * 8);
    }
}

#define SA(DB, H, KT) stage_slab(A16 + (size_t)(mb * 128 + (H)*64) * K + (KT)*64, \
                                 K, Ad[DB][H], tid)
#define SBm(DB, H, KT) stage_slab(Bw + (size_t)(nb * 128 + (H)*64) * K + (KT)*64, \
                                  K, Bd[DB][H], tid)

#define PH(DB, MH_, NH_, LA, LB, STAGE, VMC)                                   \
    phase_rw<MH_, NH_, LA, LB>(Ad[DB][MH_], Bd[DB][NH_], af, bfp, cl, q, wm, wn); \
    STAGE;                                                                     \
    SB0; __builtin_amdgcn_s_barrier(); SB0;                                    \
    phase_mm<MH_, NH_>(af, bfp, acc);                                          \
    VMC;                                                                       \
    SB0; __builtin_amdgcn_s_barrier(); SB0;

template <bool OUT_F16, bool COLSUM>
__global__ __launch_bounds__(256, 2) void gemm_kernel(
    const f16* __restrict__ A16, const f16* __restrict__ Bw,
    const float* __restrict__ bias, void* __restrict__ C_,
    float* __restrict__ colsum, int M, int N, int K) {
    __shared__ f16 Ad[2][2][64 * 64];
    __shared__ f16 Bd[2][2][64 * 64];
    const int tid = threadIdx.x;
    const int lane = tid & 63;
    const int w = tid >> 6;
    const int wm = w >> 1, wn = w & 1;
    const int q = lane >> 4, cl = lane & 15;
    const int nblk = N >> 7;
    const int cpx = (int)gridDim.x >> 3;
    const int logical = ((int)blockIdx.x & 7) * cpx + ((int)blockIdx.x >> 3);
    const int mb = logical / nblk, nb = logical % nblk;

    f32x4 acc[4][4] = {};
    f16x8 af[2][2], bfp[2][2][2];
    const int ITERS = (K >> 6) / 2;

    // prologue (verbatim slot order): d0 full + d1 half0s = 6 units
    SA(0, 0, 0); SBm(0, 0, 0); SBm(0, 1, 0); SA(0, 1, 0);
    SA(1, 0, 1); SBm(1, 0, 1);
    VM8;
    SB0; __builtin_amdgcn_s_barrier(); SB0;

#pragma unroll 1
    for (int i = 0; i < ITERS - 1; ++i) {
        const int k2 = 2 * i;
        PH(0, 0, 0, true,  true,  SA(1, 1, k2 + 1),  VM8)   // p1
        PH(0, 0, 1, false, true,  SBm(1, 1, k2 + 1), VM8)   // p2
        PH(0, 1, 0, true,  false, SA(0, 0, k2 + 2),  VMN)   // p3
        PH(0, 1, 1, false, false, SBm(0, 0, k2 + 2), VM8)   // p4
        PH(1, 0, 0, true,  true,  SBm(0, 1, k2 + 2), VM6)   // p5
        PH(1, 0, 1, false, true,  SA(0, 1, k2 + 2),  VMN)   // p6
        PH(1, 1, 0, true,  false, SA(1, 0, k2 + 3),  VMN)   // p7
        PH(1, 1, 1, false, false, SBm(1, 0, k2 + 3), VM8)   // p8
    }
    {   // epilogue iter (fences verbatim)
        const int kl = 2 * ITERS - 1;
        PH(0, 0, 0, true,  true,  SA(1, 1, kl),  VM8)
        PH(0, 0, 1, false, true,  SBm(1, 1, kl), VM8)
        PH(0, 1, 0, true,  false, VMN,           VMN)
        PH(0, 1, 1, false, false, VMN,           VM4)
        PH(1, 0, 0, true,  true,  VMN,           VM0)
        PH(1, 0, 1, false, true,  VMN,           VMN)
        PH(1, 1, 0, true,  false, VMN,           VMN)
        PH(1, 1, 1, false, false, VMN,           VMN)
    }

    // C epilogue: row = (mt7>>1)*64 + wm*32 + (mt7&1)*16 + q*4
    //             col = (nt4>>1)*64 + wn*32 + (nt4&1)*16 + cl
#pragma unroll
    for (int mt7 = 0; mt7 < 4; ++mt7) {
#pragma unroll
        for (int nt4 = 0; nt4 < 4; ++nt4) {
            int row0 = mb * 128 + (mt7 >> 1) * 64 + wm * 32 + (mt7 & 1) * 16 + q * 4;
            int col = nb * 128 + (nt4 >> 1) * 64 + wn * 32 + (nt4 & 1) * 16 + cl;
            float bv = bias[col];
#pragma unroll
            for (int r = 0; r < 4; ++r) {
                float v = acc[mt7][nt4][r] + bv;
                if (OUT_F16)
                    ((f16*)C_)[(size_t)(row0 + r) * N + col] = (f16)v;
                else
                    ((float*)C_)[(size_t)(row0 + r) * N + col] = v;
            }
        }
    }

    if (COLSUM) {
        // per-thread partials; wave covers 64 of 128 rows (wm-interleaved)
        float cs[4];
#pragma unroll
        for (int nt4 = 0; nt4 < 4; ++nt4) {
            float s = 0.f;
#pragma unroll
            for (int mt7 = 0; mt7 < 4; ++mt7)
#pragma unroll
                for (int r = 0; r < 4; ++r) s += acc[mt7][nt4][r];
            s += __shfl_xor(s, 16);
            s += __shfl_xor(s, 32);
            cs[nt4] = s;
        }
        float* S = (float*)Ad;  // 4 waves x 64 = 1KB scratch
        __syncthreads();
        if (q == 0) {
#pragma unroll
            for (int nt4 = 0; nt4 < 4; ++nt4) S[w * 64 + nt4 * 16 + cl] = cs[nt4];
        }
        __syncthreads();
        if (tid < 128) {
            int c = tid;
            int NHq = c >> 6, wn2 = (c >> 5) & 1, sub = (c >> 4) & 1, cll = c & 15;
            int idx = (NHq * 2 + sub) * 16 + cll;
            int col = nb * 128 + c;
            colsum[(size_t)mb * N + col] =
                S[wn2 * 64 + idx] + S[(2 + wn2) * 64 + idx] + 128.f * bias[col];
        }
    }
}

// ---------------- router (colsum now per-128-row block: sum row pairs) -----
__global__ __launch_bounds__(64) void router_kernel(const float* __restrict__ colsum,
                                                    const float* __restrict__ emb,
                                                    float* __restrict__ ew) {
    const int t = blockIdx.x;
    const int bn = t >> 3, h = t & 7;
    const int lane = threadIdx.x;
    float acc = 0.f;
    const float* p = colsum + (size_t)bn * 2048 + h * 128;
    if (lane < 16) {
        const float sc = 1.f / 256.f;
        for (int d = 0; d < 128; ++d)
            acc = fmaf((p[d] + p[d + 1024]) * sc, emb[d * 16 + lane], acc);
    }
    float m = acc;
#pragma unroll
    for (int o = 8; o; o >>= 1) m = fmaxf(m, __shfl_xor(m, o));
    float pr = __expf(acc - m);
    float s = pr;
#pragma unroll
    for (int o = 8; o; o >>= 1) s += __shfl_xor(s, o);
    if (lane < 16) ew[t * 16 + lane] = pr / s;
}

// ---------------- expert mixture v3: SGPR weights, no LDS ----------------
__global__ __launch_bounds__(256) void mix_kernel(const float* __restrict__ ew,
                                                  const float* __restrict__ FL,
                                                  const float* __restrict__ SL,
                                                  f16* __restrict__ m1h,
                                                  f16* __restrict__ m2h) {
    const int bid = blockIdx.x;
    const int which = bid >> 10;
    const int tg = (bid >> 6) & 15;
    const int chunk = bid & 63;
    const float* src = which ? SL : FL;
    f16* dst = which ? m2h : m1h;
    const int tid = threadIdx.x;
    const int e0 = chunk * 1024 + tid * 4;

    f32x4 fl[16];
#pragma unroll
    for (int e = 0; e < 16; ++e)
        fl[e] = *(const f32x4*)(src + (size_t)e * 65536 + e0);

    const float* wbase = ew + (size_t)tg * 32 * 16;
    float wc[16];
#pragma unroll
    for (int e = 0; e < 16; ++e) wc[e] = wbase[e];

#pragma unroll 1
    for (int tt = 0; tt < 32; ++tt) {
        float wn2[16];
        if (tt < 31) {
#pragma unroll
            for (int e = 0; e < 16; ++e) wn2[e] = wbase[(tt + 1) * 16 + e];
        }
        f32x4 a = {0.f, 0.f, 0.f, 0.f};
#pragma unroll
        for (int e = 0; e < 16; ++e) {
            a[0] = fmaf(wc[e], fl[e][0], a[0]);
            a[1] = fmaf(wc[e], fl[e][1], a[1]);
            a[2] = fmaf(wc[e], fl[e][2], a[2]);
            a[3] = fmaf(wc[e], fl[e][3], a[3]);
        }
        f16x4 h;
        h[0] = (f16)a[0]; h[1] = (f16)a[1]; h[2] = (f16)a[2]; h[3] = (f16)a[3];
        *(f16x4*)(dst + (size_t)(tg * 32 + tt) * 65536 + e0) = h;
        if (tt < 31) {
#pragma unroll
            for (int e = 0; e < 16; ++e) wc[e] = wn2[e];
        }
    }
}

// ============ MLP v5 (plateau best: ~50us) ============
__device__ __forceinline__ void stage_m1c(const f16* m1c, f16* dst, int tid) {
#pragma unroll
    for (int j = 0; j < 4; ++j) {
        int idx = j * 256 + tid;
        int row = idx >> 4, g = idx & 15;
        glds16(m1c + (size_t)row * 128 + (g ^ (row & 7)) * 8, dst + (idx & ~63) * 8);
    }
}
__device__ __forceinline__ void stage_m2c(const f16* m2c, f16* dst, int tid) {
#pragma unroll
    for (int j = 0; j < 4; ++j) {
        int idx = j * 256 + tid;
        int row = idx >> 3, g = idx & 7;
        glds16(m2c + (size_t)row * 512 + (g ^ (row & 7)) * 8, dst + (idx & ~63) * 8);
    }
}

__global__ __launch_bounds__(256) void mlp_kernel(const f16* __restrict__ Xg,
                                                  const f16* __restrict__ m1h,
                                                  const f16* __restrict__ m2h,
                                                  f16* __restrict__ Yg) {
    __shared__ f16 Ws[128 * 64];
    __shared__ f16 Hs[128 * 64];
    const int cpx = (int)gridDim.x >> 3;
    const int logical = ((int)blockIdx.x & 7) * cpx + ((int)blockIdx.x >> 3);
    const int t = logical >> 1, lh = logical & 1;
    const int n = (t >> 3) & 15;
    const int tm = (n > 0) ? (t - 8) : t;
    const int tid = threadIdx.x;
    const int lane = tid & 63, w = tid >> 6;
    const int q = lane >> 4, cl = lane & 15;
    const int l0 = w * 32;

    const f16* Xsrc = Xg + (size_t)t * 32768 + lh * 16384;
    const f16* m1b = m1h + (size_t)tm * 65536;
    const f16* m2b = m2h + (size_t)tm * 65536;

    stage_m1c(m1b, Ws, tid);
    f16x8 xf[2][4];
#pragma unroll
    for (int lt = 0; lt < 2; ++lt) {
        int l = l0 + lt * 16 + cl;
#pragma unroll
        for (int ks = 0; ks < 4; ++ks)
            xf[lt][ks] = *(const f16x8*)(Xsrc + (size_t)l * 128 + ks * 32 + q * 8);
    }
    __syncthreads();

    f32x4 acc2[2][8] = {};
#pragma unroll 1
    for (int ic = 0; ic < 8; ++ic) {
#pragma unroll
        for (int it = 0; it < 4; ++it) {
            f16x8 af2[4];
#pragma unroll
            for (int ks = 0; ks < 4; ++ks) {
                int r = it * 16 + cl;
                af2[ks] = *(const f16x8*)&Ws[r * 128 +
                                             (((ks * 4 + q) ^ (r & 7))) * 8];
            }
            f32x4 a1[2] = {};
#pragma unroll
            for (int ks = 0; ks < 4; ++ks)
#pragma unroll
                for (int lt = 0; lt < 2; ++lt)
                    a1[lt] = MFMA16(af2[ks], xf[lt][ks], a1[lt]);
            int gi = 2 * it + (q >> 1);
            int sub = (q & 1) * 8;
#pragma unroll
            for (int lt = 0; lt < 2; ++lt) {
                int l = l0 + lt * 16 + cl;
                f16x4 hv;
                hv[0] = (f16)fmaxf(a1[lt][0], 0.f);
                hv[1] = (f16)fmaxf(a1[lt][1], 0.f);
                hv[2] = (f16)fmaxf(a1[lt][2], 0.f);
                hv[3] = (f16)fmaxf(a1[lt][3], 0.f);
                *(f16x4*)((char*)Hs + (size_t)l * 128 + ((gi ^ (l & 7)) << 4) + sub) =
                    hv;
            }
        }
        __syncthreads();
        stage_m2c(m2b + ic * 64, Ws, tid);
        __syncthreads();

        f16x8 hf[2][2];
#pragma unroll
        for (int lt = 0; lt < 2; ++lt)
#pragma unroll
            for (int ks = 0; ks < 2; ++ks) {
                int l = l0 + lt * 16 + cl;
                hf[lt][ks] =
                    *(const f16x8*)&Hs[l * 64 + (((ks * 4 + q) ^ (l & 7))) * 8];
            }
#pragma unroll
        for (int nt = 0; nt < 8; ++nt) {
            f16x8 bf2[2];
#pragma unroll
            for (int ks = 0; ks < 2; ++ks) {
                int d = nt * 16 + cl;
                bf2[ks] = *(const f16x8*)&Ws[d * 64 +
                                             (((ks * 4 + q) ^ (d & 7))) * 8];
            }
#pragma unroll
            for (int lt = 0; lt < 2; ++lt)
#pragma unroll
                for (int ks = 0; ks < 2; ++ks)
                    acc2[lt][nt] = MFMA16(hf[lt][ks], bf2[ks], acc2[lt][nt]);
        }
        __syncthreads();
        if (ic < 7) {
            stage_m1c(m1b + (size_t)(ic + 1) * 8192, Ws, tid);
            __syncthreads();
        }
    }

    f16* Yb = Yg + (size_t)t * 32768 + lh * 16384;
#pragma unroll
    for (int lt = 0; lt < 2; ++lt) {
#pragma unroll
        for (int nt = 0; nt < 8; ++nt) {
            int lr = l0 + lt * 16 + q * 4;
            int d = nt * 16 + cl;
#pragma unroll
            for (int r = 0; r < 4; ++r)
                Yb[(size_t)(lr + r) * 128 + d] = (f16)acc2[lt][nt][r];
        }
    }
}

extern "C" void kernel_launch(void* const* d_in, const int* in_sizes, int n_in,
                              void* d_out, int out_size, void* d_ws, size_t ws_size,
                              hipStream_t stream) {
    const float* x    = (const float*)d_in[0];
    const float* W_mh = (const float*)d_in[1];
    const float* b_mh = (const float*)d_in[2];
    const float* W_mg = (const float*)d_in[3];
    const float* b_mg = (const float*)d_in[4];
    const float* emb  = (const float*)d_in[5];
    const float* FL   = (const float*)d_in[6];
    const float* SL   = (const float*)d_in[7];

    char* ws = (char*)d_ws;
    f16*   X1h  = (f16*)(ws + 0);
    f16*   m1h  = (f16*)(ws + 33554432);
    f16*   X0h  = (f16*)(ws + 33554432);   // aliases m1h (dead interval)
    f16*   m2h  = (f16*)(ws + 100663296);
    f16*   Wmhh = (f16*)(ws + 167772160);
    f16*   Wmgh = (f16*)(ws + 169869312);
    float* csum = (float*)(ws + 171966464); // 128 x 1024 f32 = 512KB
    float* ew   = (float*)(ws + 172490752);

    cvt_kernel<<<512, 256, 0, stream>>>(W_mh, Wmhh, 1048576);
    cvt_kernel<<<512, 256, 0, stream>>>(W_mg, Wmgh, 1048576);
    cvt_kernel<<<8192, 256, 0, stream>>>(x, X0h, 16777216);
    gemm_kernel<true, true><<<1024, 256, 0, stream>>>(X0h, Wmhh, b_mh, X1h,
                                                      csum, 16384, 1024, 1024);
    router_kernel<<<512, 64, 0, stream>>>(csum, emb, ew);
    mix_kernel<<<2048, 256, 0, stream>>>(ew, FL, SL, m1h, m2h);
    mlp_kernel<<<1024, 256, 0, stream>>>(X1h, m1h, m2h, X1h);
    gemm_kernel<false, false><<<1024, 256, 0, stream>>>(X1h, Wmgh, b_mg, d_out,
                                                        nullptr, 16384, 1024, 1024);
}

// Round 18
// 193.882 us; speedup vs baseline: 1.0568x; 1.0568x over previous
//
#include <hip/hip_runtime.h>
#include <hip/hip_bf16.h>

typedef _Float16 f16;
typedef f16 f16x2 __attribute__((ext_vector_type(2)));
typedef f16 f16x4 __attribute__((ext_vector_type(4)));
typedef f16 f16x8 __attribute__((ext_vector_type(8)));
typedef float f32x2 __attribute__((ext_vector_type(2)));
typedef float f32x4 __attribute__((ext_vector_type(4)));

#define MFMA16(a, b, c) __builtin_amdgcn_mfma_f32_16x16x32_f16(a, b, c, 0, 0, 0)

__device__ __forceinline__ void glds16(const void* g, void* l) {
    __builtin_amdgcn_global_load_lds(
        (const __attribute__((address_space(1))) unsigned int*)g,
        (__attribute__((address_space(3))) unsigned int*)l, 16, 0, 0);
}

#define VM8 asm volatile("s_waitcnt vmcnt(8)" ::: "memory")
#define VM6 asm volatile("s_waitcnt vmcnt(6)" ::: "memory")
#define VM4 asm volatile("s_waitcnt vmcnt(4)" ::: "memory")
#define VM0 asm volatile("s_waitcnt vmcnt(0)" ::: "memory")
#define VMN do {} while (0)
#define SB0 __builtin_amdgcn_sched_barrier(0)

// ---------------- merged f32 -> f16 convert (W_mh | W_mg | x) ----------------
__global__ __launch_bounds__(256) void cvt_all_kernel(
    const float* __restrict__ W_mh, const float* __restrict__ W_mg,
    const float* __restrict__ x, f16* __restrict__ dWmh,
    f16* __restrict__ dWmg, f16* __restrict__ dx) {
    const int b = blockIdx.x;
    const float* s;
    f16* d;
    int i;
    if (b < 512) {
        s = W_mh; d = dWmh; i = (b * 256 + (int)threadIdx.x) * 8;
    } else if (b < 1024) {
        s = W_mg; d = dWmg; i = ((b - 512) * 256 + (int)threadIdx.x) * 8;
    } else {
        s = x; d = dx; i = ((b - 1024) * 256 + (int)threadIdx.x) * 8;
    }
    float4 a = *(const float4*)(s + i);
    float4 bb = *(const float4*)(s + i + 4);
    f16x8 h;
    h[0] = (f16)a.x; h[1] = (f16)a.y; h[2] = (f16)a.z; h[3] = (f16)a.w;
    h[4] = (f16)bb.x; h[5] = (f16)bb.y; h[6] = (f16)bb.z; h[7] = (f16)bb.w;
    *(f16x8*)(d + i) = h;
}

// ============ GEMM 256x256 8-phase (T2+T3+T4+T5) — proven R11/R16 ============
template <int MH, int NH, bool LOADA>
__device__ __forceinline__ void phase_rw(const f16* Aslab, const f16* Bslab,
                                         f16x8 (&af)[4][2], f16x8 (&bf)[2][2],
                                         int cl, int q, int wm, int wn) {
    if (LOADA) {
#pragma unroll
        for (int mt = 0; mt < 4; ++mt)
#pragma unroll
            for (int ks = 0; ks < 2; ++ks)
                af[mt][ks] =
                    *(const f16x8*)&Aslab[(wm * 64 + mt * 16 + cl) * 64 +
                                          ((ks * 4 + q) ^ (cl & 7)) * 8];
    }
#pragma unroll
    for (int nt = 0; nt < 2; ++nt)
#pragma unroll
        for (int ks = 0; ks < 2; ++ks)
            bf[nt][ks] = *(const f16x8*)&Bslab[(wn * 32 + nt * 16 + cl) * 64 +
                                               ((ks * 4 + q) ^ (cl & 7)) * 8];
}

template <int MH, int NH>
__device__ __forceinline__ void phase_mm(f16x8 (&af)[4][2], f16x8 (&bf)[2][2],
                                         f32x4 (&acc)[8][4]) {
    __builtin_amdgcn_s_setprio(1);
#pragma unroll
    for (int mt = 0; mt < 4; ++mt)
#pragma unroll
        for (int nt = 0; nt < 2; ++nt)
#pragma unroll
            for (int ks = 0; ks < 2; ++ks)
                acc[MH * 4 + mt][NH * 2 + nt] =
                    MFMA16(af[mt][ks], bf[nt][ks], acc[MH * 4 + mt][NH * 2 + nt]);
    __builtin_amdgcn_s_setprio(0);
}

__device__ __forceinline__ void stage_half(const f16* gsrc, int ldk, f16* ldst,
                                           int w, int lane) {
#pragma unroll
    for (int j = 0; j < 2; ++j) {
        int idx = j * 512 + w * 64 + lane;
        int rr = idx >> 3;
        int gs = (idx & 7) ^ (rr & 7);
        glds16(gsrc + (size_t)rr * ldk + gs * 8, ldst + (j * 512 + w * 64) * 8);
    }
}

#define SA(DB, H, KT) stage_half(A16 + (size_t)(mb * 256 + (H)*128) * K + (KT)*64, \
                                 K, Ad[DB][H], w, lane)
#define SBm(DB, H, KT) stage_half(Bw + (size_t)(nb * 256 + (H)*128) * K + (KT)*64, \
                                  K, Bd[DB][H], w, lane)

#define PH(DB, MH, NH, LA, STAGE, VMC)                                    \
    phase_rw<MH, NH, LA>(Ad[DB][MH], Bd[DB][NH], af, bf, cl, q, wm, wn);  \
    STAGE;                                                                \
    SB0; __builtin_amdgcn_s_barrier(); SB0;                               \
    phase_mm<MH, NH>(af, bf, acc);                                        \
    VMC;                                                                  \
    SB0; __builtin_amdgcn_s_barrier(); SB0;

template <bool OUT_F16, bool COLSUM>
__global__ __launch_bounds__(512, 2) void gemm256_kernel(
    const f16* __restrict__ A16, const f16* __restrict__ Bw,
    const float* __restrict__ bias, void* __restrict__ C_,
    float* __restrict__ colsum, int M, int N, int K) {
    __shared__ f16 Ad[2][2][128 * 64];
    __shared__ f16 Bd[2][2][128 * 64];
    const int tid = threadIdx.x;
    const int lane = tid & 63;
    const int w = tid >> 6;
    const int wm = w >> 2, wn = w & 3;
    const int q = lane >> 4, cl = lane & 15;
    const int nblk = N >> 8;
    const int cpx = (int)gridDim.x >> 3;
    const int logical = ((int)blockIdx.x & 7) * cpx + ((int)blockIdx.x >> 3);
    const int mb = logical / nblk, nb = logical % nblk;

    f32x4 acc[8][4] = {};
    f16x8 af[4][2], bf[2][2];
    const int ITERS = (K >> 6) / 2;

    SA(0, 0, 0); SBm(0, 0, 0); SBm(0, 1, 0); SA(0, 1, 0);
    SA(1, 0, 1); SBm(1, 0, 1);
    VM8;
    SB0; __builtin_amdgcn_s_barrier(); SB0;

#pragma unroll 1
    for (int i = 0; i < ITERS - 1; ++i) {
        const int k2 = 2 * i;
        PH(0, 0, 0, true,  SA(1, 1, k2 + 1),  VM8)
        PH(0, 0, 1, false, SBm(1, 1, k2 + 1), VM8)
        PH(0, 1, 0, true,  SA(0, 0, k2 + 2),  VMN)
        PH(0, 1, 1, false, SBm(0, 0, k2 + 2), VM8)
        PH(1, 0, 0, true,  SBm(0, 1, k2 + 2), VM6)
        PH(1, 0, 1, false, SA(0, 1, k2 + 2),  VMN)
        PH(1, 1, 0, true,  SA(1, 0, k2 + 3),  VMN)
        PH(1, 1, 1, false, SBm(1, 0, k2 + 3), VM8)
    }
    {
        const int kl = 2 * ITERS - 1;
        PH(0, 0, 0, true,  SA(1, 1, kl),  VM8)
        PH(0, 0, 1, false, SBm(1, 1, kl), VM8)
        PH(0, 1, 0, true,  VMN,           VMN)
        PH(0, 1, 1, false, VMN,           VM4)
        PH(1, 0, 0, true,  VMN,           VM0)
        PH(1, 0, 1, false, VMN,           VMN)
        PH(1, 1, 0, true,  VMN,           VMN)
        PH(1, 1, 1, false, VMN,           VMN)
    }

    // C epilogue (+bias)
#pragma unroll
    for (int mt7 = 0; mt7 < 8; ++mt7) {
#pragma unroll
        for (int nt4 = 0; nt4 < 4; ++nt4) {
            int row0 = mb * 256 + (mt7 >> 2) * 128 + wm * 64 + (mt7 & 3) * 16 + q * 4;
            int col = nb * 256 + (nt4 >> 1) * 128 + wn * 32 + (nt4 & 1) * 16 + cl;
            float bv = bias[col];
#pragma unroll
            for (int r = 0; r < 4; ++r) {
                float v = acc[mt7][nt4][r] + bv;
                if (OUT_F16)
                    ((f16*)C_)[(size_t)(row0 + r) * N + col] = (f16)v;
                else
                    ((float*)C_)[(size_t)(row0 + r) * N + col] = v;
            }
        }
    }

    if (COLSUM) {
        float cs[4];
#pragma unroll
        for (int nt4 = 0; nt4 < 4; ++nt4) {
            int col = nb * 256 + (nt4 >> 1) * 128 + wn * 32 + (nt4 & 1) * 16 + cl;
            float s = 32.f * bias[col];
#pragma unroll
            for (int mt7 = 0; mt7 < 8; ++mt7)
#pragma unroll
                for (int r = 0; r < 4; ++r) s += acc[mt7][nt4][r];
            s += __shfl_xor(s, 16);
            s += __shfl_xor(s, 32);
            cs[nt4] = s;
        }
        float* S = (float*)Ad;
        __syncthreads();
        if (q == 0) {
#pragma unroll
            for (int nt4 = 0; nt4 < 4; ++nt4) S[w * 64 + nt4 * 16 + cl] = cs[nt4];
        }
        __syncthreads();
        if (tid < 256) {
            int col = tid;
            int quad = col >> 7, ciq = col & 127;
            int wn2 = ciq >> 5, sub = (ciq >> 4) & 1, cll = col & 15;
            int idx = wn2 * 64 + (quad * 2 + sub) * 16 + cll;
            colsum[(size_t)mb * N + nb * 256 + col] = S[idx] + S[256 + idx];
        }
    }
}

// ---------------- router (reads fused colsum; scale 1/256) ----------------
__global__ __launch_bounds__(64) void router_kernel(const float* __restrict__ colsum,
                                                    const float* __restrict__ emb,
                                                    float* __restrict__ ew) {
    const int t = blockIdx.x;
    const int bn = t >> 3, h = t & 7;
    const int lane = threadIdx.x;
    float acc = 0.f;
    const float* p = colsum + (size_t)bn * 1024 + h * 128;
    if (lane < 16) {
        const float sc = 1.f / 256.f;
        for (int d = 0; d < 128; ++d)
            acc = fmaf(p[d] * sc, emb[d * 16 + lane], acc);
    }
    float m = acc;
#pragma unroll
    for (int o = 8; o; o >>= 1) m = fmaxf(m, __shfl_xor(m, o));
    float pr = __expf(acc - m);
    float s = pr;
#pragma unroll
    for (int o = 8; o; o >>= 1) s += __shfl_xor(s, o);
    if (lane < 16) ew[t * 16 + lane] = pr / s;
}

// ---------------- expert mixture v3: SGPR weights, no LDS ----------------
__global__ __launch_bounds__(256) void mix_kernel(const float* __restrict__ ew,
                                                  const float* __restrict__ FL,
                                                  const float* __restrict__ SL,
                                                  f16* __restrict__ m1h,
                                                  f16* __restrict__ m2h) {
    const int bid = blockIdx.x;
    const int which = bid >> 10;
    const int tg = (bid >> 6) & 15;
    const int chunk = bid & 63;
    const float* src = which ? SL : FL;
    f16* dst = which ? m2h : m1h;
    const int tid = threadIdx.x;
    const int e0 = chunk * 1024 + tid * 4;

    f32x4 fl[16];
#pragma unroll
    for (int e = 0; e < 16; ++e)
        fl[e] = *(const f32x4*)(src + (size_t)e * 65536 + e0);

    const float* wbase = ew + (size_t)tg * 32 * 16;
    float wc[16];
#pragma unroll
    for (int e = 0; e < 16; ++e) wc[e] = wbase[e];

#pragma unroll 1
    for (int tt = 0; tt < 32; ++tt) {
        float wn2[16];
        if (tt < 31) {
#pragma unroll
            for (int e = 0; e < 16; ++e) wn2[e] = wbase[(tt + 1) * 16 + e];
        }
        f32x4 a = {0.f, 0.f, 0.f, 0.f};
#pragma unroll
        for (int e = 0; e < 16; ++e) {
            a[0] = fmaf(wc[e], fl[e][0], a[0]);
            a[1] = fmaf(wc[e], fl[e][1], a[1]);
            a[2] = fmaf(wc[e], fl[e][2], a[2]);
            a[3] = fmaf(wc[e], fl[e][3], a[3]);
        }
        f16x4 h;
        h[0] = (f16)a[0]; h[1] = (f16)a[1]; h[2] = (f16)a[2]; h[3] = (f16)a[3];
        *(f16x4*)(dst + (size_t)(tg * 32 + tt) * 65536 + e0) = h;
        if (tt < 31) {
#pragma unroll
            for (int e = 0; e < 16; ++e) wc[e] = wn2[e];
        }
    }
}

// ============ MLP v5 (plateau best: ~50us) ============
__device__ __forceinline__ void stage_m1c(const f16* m1c, f16* dst, int tid) {
#pragma unroll
    for (int j = 0; j < 4; ++j) {
        int idx = j * 256 + tid;
        int row = idx >> 4, g = idx & 15;
        glds16(m1c + (size_t)row * 128 + (g ^ (row & 7)) * 8, dst + (idx & ~63) * 8);
    }
}
__device__ __forceinline__ void stage_m2c(const f16* m2c, f16* dst, int tid) {
#pragma unroll
    for (int j = 0; j < 4; ++j) {
        int idx = j * 256 + tid;
        int row = idx >> 3, g = idx & 7;
        glds16(m2c + (size_t)row * 512 + (g ^ (row & 7)) * 8, dst + (idx & ~63) * 8);
    }
}

__global__ __launch_bounds__(256) void mlp_kernel(const f16* __restrict__ Xg,
                                                  const f16* __restrict__ m1h,
                                                  const f16* __restrict__ m2h,
                                                  f16* __restrict__ Yg) {
    __shared__ f16 Ws[128 * 64];
    __shared__ f16 Hs[128 * 64];
    const int cpx = (int)gridDim.x >> 3;
    const int logical = ((int)blockIdx.x & 7) * cpx + ((int)blockIdx.x >> 3);
    const int t = logical >> 1, lh = logical & 1;
    const int n = (t >> 3) & 15;
    const int tm = (n > 0) ? (t - 8) : t;
    const int tid = threadIdx.x;
    const int lane = tid & 63, w = tid >> 6;
    const int q = lane >> 4, cl = lane & 15;
    const int l0 = w * 32;

    const f16* Xsrc = Xg + (size_t)t * 32768 + lh * 16384;
    const f16* m1b = m1h + (size_t)tm * 65536;
    const f16* m2b = m2h + (size_t)tm * 65536;

    stage_m1c(m1b, Ws, tid);
    f16x8 xf[2][4];
#pragma unroll
    for (int lt = 0; lt < 2; ++lt) {
        int l = l0 + lt * 16 + cl;
#pragma unroll
        for (int ks = 0; ks < 4; ++ks)
            xf[lt][ks] = *(const f16x8*)(Xsrc + (size_t)l * 128 + ks * 32 + q * 8);
    }
    __syncthreads();

    f32x4 acc2[2][8] = {};
#pragma unroll 1
    for (int ic = 0; ic < 8; ++ic) {
#pragma unroll
        for (int it = 0; it < 4; ++it) {
            f16x8 af2[4];
#pragma unroll
            for (int ks = 0; ks < 4; ++ks) {
                int r = it * 16 + cl;
                af2[ks] = *(const f16x8*)&Ws[r * 128 +
                                             (((ks * 4 + q) ^ (r & 7))) * 8];
            }
            f32x4 a1[2] = {};
#pragma unroll
            for (int ks = 0; ks < 4; ++ks)
#pragma unroll
                for (int lt = 0; lt < 2; ++lt)
                    a1[lt] = MFMA16(af2[ks], xf[lt][ks], a1[lt]);
            int gi = 2 * it + (q >> 1);
            int sub = (q & 1) * 8;
#pragma unroll
            for (int lt = 0; lt < 2; ++lt) {
                int l = l0 + lt * 16 + cl;
                f16x4 hv;
                hv[0] = (f16)fmaxf(a1[lt][0], 0.f);
                hv[1] = (f16)fmaxf(a1[lt][1], 0.f);
                hv[2] = (f16)fmaxf(a1[lt][2], 0.f);
                hv[3] = (f16)fmaxf(a1[lt][3], 0.f);
                *(f16x4*)((char*)Hs + (size_t)l * 128 + ((gi ^ (l & 7)) << 4) + sub) =
                    hv;
            }
        }
        __syncthreads();
        stage_m2c(m2b + ic * 64, Ws, tid);
        __syncthreads();

        f16x8 hf[2][2];
#pragma unroll
        for (int lt = 0; lt < 2; ++lt)
#pragma unroll
            for (int ks = 0; ks < 2; ++ks) {
                int l = l0 + lt * 16 + cl;
                hf[lt][ks] =
                    *(const f16x8*)&Hs[l * 64 + (((ks * 4 + q) ^ (l & 7))) * 8];
            }
#pragma unroll
        for (int nt = 0; nt < 8; ++nt) {
            f16x8 bf2[2];
#pragma unroll
            for (int ks = 0; ks < 2; ++ks) {
                int d = nt * 16 + cl;
                bf2[ks] = *(const f16x8*)&Ws[d * 64 +
                                             (((ks * 4 + q) ^ (d & 7))) * 8];
            }
#pragma unroll
            for (int lt = 0; lt < 2; ++lt)
#pragma unroll
                for (int ks = 0; ks < 2; ++ks)
                    acc2[lt][nt] = MFMA16(hf[lt][ks], bf2[ks], acc2[lt][nt]);
        }
        __syncthreads();
        if (ic < 7) {
            stage_m1c(m1b + (size_t)(ic + 1) * 8192, Ws, tid);
            __syncthreads();
        }
    }

    f16* Yb = Yg + (size_t)t * 32768 + lh * 16384;
#pragma unroll
    for (int lt = 0; lt < 2; ++lt) {
#pragma unroll
        for (int nt = 0; nt < 8; ++nt) {
            int lr = l0 + lt * 16 + q * 4;
            int d = nt * 16 + cl;
#pragma unroll
            for (int r = 0; r < 4; ++r)
                Yb[(size_t)(lr + r) * 128 + d] = (f16)acc2[lt][nt][r];
        }
    }
}

extern "C" void kernel_launch(void* const* d_in, const int* in_sizes, int n_in,
                              void* d_out, int out_size, void* d_ws, size_t ws_size,
                              hipStream_t stream) {
    const float* x    = (const float*)d_in[0];
    const float* W_mh = (const float*)d_in[1];
    const float* b_mh = (const float*)d_in[2];
    const float* W_mg = (const float*)d_in[3];
    const float* b_mg = (const float*)d_in[4];
    const float* emb  = (const float*)d_in[5];
    const float* FL   = (const float*)d_in[6];
    const float* SL   = (const float*)d_in[7];

    char* ws = (char*)d_ws;
    f16*   X1h  = (f16*)(ws + 0);
    f16*   m1h  = (f16*)(ws + 33554432);
    f16*   X0h  = (f16*)(ws + 33554432);   // aliases m1h (dead interval)
    f16*   m2h  = (f16*)(ws + 100663296);
    f16*   Wmhh = (f16*)(ws + 167772160);
    f16*   Wmgh = (f16*)(ws + 169869312);
    float* csum = (float*)(ws + 171966464); // 64 x 1024 f32 = 256KB
    float* ew   = (float*)(ws + 172228608);

    cvt_all_kernel<<<9216, 256, 0, stream>>>(W_mh, W_mg, x, Wmhh, Wmgh, X0h);
    gemm256_kernel<true, true><<<256, 512, 0, stream>>>(X0h, Wmhh, b_mh, X1h,
                                                        csum, 16384, 1024, 1024);
    router_kernel<<<512, 64, 0, stream>>>(csum, emb, ew);
    mix_kernel<<<2048, 256, 0, stream>>>(ew, FL, SL, m1h, m2h);
    mlp_kernel<<<1024, 256, 0, stream>>>(X1h, m1h, m2h, X1h);
    gemm256_kernel<false, false><<<256, 512, 0, stream>>>(X1h, Wmgh, b_mg, d_out,
                                                          nullptr, 16384, 1024, 1024);
}

// Round 19
// 192.171 us; speedup vs baseline: 1.0662x; 1.0089x over previous
//
#include <hip/hip_runtime.h>
#include <hip/hip_bf16.h>

typedef _Float16 f16;
typedef f16 f16x2 __attribute__((ext_vector_type(2)));
typedef f16 f16x4 __attribute__((ext_vector_type(4)));
typedef f16 f16x8 __attribute__((ext_vector_type(8)));
typedef float f32x2 __attribute__((ext_vector_type(2)));
typedef float f32x4 __attribute__((ext_vector_type(4)));

#define MFMA16(a, b, c) __builtin_amdgcn_mfma_f32_16x16x32_f16(a, b, c, 0, 0, 0)

__device__ __forceinline__ void glds16(const void* g, void* l) {
    __builtin_amdgcn_global_load_lds(
        (const __attribute__((address_space(1))) unsigned int*)g,
        (__attribute__((address_space(3))) unsigned int*)l, 16, 0, 0);
}

#define VM8 asm volatile("s_waitcnt vmcnt(8)" ::: "memory")
#define VM6 asm volatile("s_waitcnt vmcnt(6)" ::: "memory")
#define VM4 asm volatile("s_waitcnt vmcnt(4)" ::: "memory")
#define VM0 asm volatile("s_waitcnt vmcnt(0)" ::: "memory")
#define VMN do {} while (0)
#define SB0 __builtin_amdgcn_sched_barrier(0)

// ---------------- merged f32 -> f16 convert (W_mh | W_mg | x) ----------------
__global__ __launch_bounds__(256) void cvt_all_kernel(
    const float* __restrict__ W_mh, const float* __restrict__ W_mg,
    const float* __restrict__ x, f16* __restrict__ dWmh,
    f16* __restrict__ dWmg, f16* __restrict__ dx) {
    const int b = blockIdx.x;
    const float* s;
    f16* d;
    int i;
    if (b < 512) {
        s = W_mh; d = dWmh; i = (b * 256 + (int)threadIdx.x) * 8;
    } else if (b < 1024) {
        s = W_mg; d = dWmg; i = ((b - 512) * 256 + (int)threadIdx.x) * 8;
    } else {
        s = x; d = dx; i = ((b - 1024) * 256 + (int)threadIdx.x) * 8;
    }
    float4 a = *(const float4*)(s + i);
    float4 bb = *(const float4*)(s + i + 4);
    f16x8 h;
    h[0] = (f16)a.x; h[1] = (f16)a.y; h[2] = (f16)a.z; h[3] = (f16)a.w;
    h[4] = (f16)bb.x; h[5] = (f16)bb.y; h[6] = (f16)bb.z; h[7] = (f16)bb.w;
    *(f16x8*)(d + i) = h;
}

// ============ GEMM 256x256 8-phase (T2+T3+T4+T5) + B-frag persistence =======
// Proven R16 schedule, fences/stage slots byte-identical. NEW: bfp[NH] loaded
// only on NH-first phases (p1,p2,p5,p6), reused on (p3,p4,p7,p8) — LDS reads
// 64->48 per iter (-25%). WAR safe: Bd[d][NH] last read 1 phase before its
// restage slot (one phase LATER than the existing af-persistence pattern).
template <int MH, int NH, bool LOADA, bool LOADB>
__device__ __forceinline__ void phase_rw(const f16* Aslab, const f16* Bslab,
                                         f16x8 (&af)[4][2], f16x8 (&bfp)[2][2][2],
                                         int cl, int q, int wm, int wn) {
    if (LOADA) {
#pragma unroll
        for (int mt = 0; mt < 4; ++mt)
#pragma unroll
            for (int ks = 0; ks < 2; ++ks)
                af[mt][ks] =
                    *(const f16x8*)&Aslab[(wm * 64 + mt * 16 + cl) * 64 +
                                          ((ks * 4 + q) ^ (cl & 7)) * 8];
    }
    if (LOADB) {
#pragma unroll
        for (int nt = 0; nt < 2; ++nt)
#pragma unroll
            for (int ks = 0; ks < 2; ++ks)
                bfp[NH][nt][ks] =
                    *(const f16x8*)&Bslab[(wn * 32 + nt * 16 + cl) * 64 +
                                          ((ks * 4 + q) ^ (cl & 7)) * 8];
    }
}

template <int MH, int NH>
__device__ __forceinline__ void phase_mm(f16x8 (&af)[4][2], f16x8 (&bfp)[2][2][2],
                                         f32x4 (&acc)[8][4]) {
    __builtin_amdgcn_s_setprio(1);
#pragma unroll
    for (int mt = 0; mt < 4; ++mt)
#pragma unroll
        for (int nt = 0; nt < 2; ++nt)
#pragma unroll
            for (int ks = 0; ks < 2; ++ks)
                acc[MH * 4 + mt][NH * 2 + nt] =
                    MFMA16(af[mt][ks], bfp[NH][nt][ks],
                           acc[MH * 4 + mt][NH * 2 + nt]);
    __builtin_amdgcn_s_setprio(0);
}

__device__ __forceinline__ void stage_half(const f16* gsrc, int ldk, f16* ldst,
                                           int w, int lane) {
#pragma unroll
    for (int j = 0; j < 2; ++j) {
        int idx = j * 512 + w * 64 + lane;
        int rr = idx >> 3;
        int gs = (idx & 7) ^ (rr & 7);
        glds16(gsrc + (size_t)rr * ldk + gs * 8, ldst + (j * 512 + w * 64) * 8);
    }
}

#define SA(DB, H, KT) stage_half(A16 + (size_t)(mb * 256 + (H)*128) * K + (KT)*64, \
                                 K, Ad[DB][H], w, lane)
#define SBm(DB, H, KT) stage_half(Bw + (size_t)(nb * 256 + (H)*128) * K + (KT)*64, \
                                  K, Bd[DB][H], w, lane)

#define PH(DB, MH, NH, LA, LB, STAGE, VMC)                                     \
    phase_rw<MH, NH, LA, LB>(Ad[DB][MH], Bd[DB][NH], af, bfp, cl, q, wm, wn);  \
    STAGE;                                                                     \
    SB0; __builtin_amdgcn_s_barrier(); SB0;                                    \
    phase_mm<MH, NH>(af, bfp, acc);                                            \
    VMC;                                                                       \
    SB0; __builtin_amdgcn_s_barrier(); SB0;

template <bool OUT_F16, bool COLSUM>
__global__ __launch_bounds__(512, 2) void gemm256_kernel(
    const f16* __restrict__ A16, const f16* __restrict__ Bw,
    const float* __restrict__ bias, void* __restrict__ C_,
    float* __restrict__ colsum, int M, int N, int K) {
    __shared__ f16 Ad[2][2][128 * 64];
    __shared__ f16 Bd[2][2][128 * 64];
    const int tid = threadIdx.x;
    const int lane = tid & 63;
    const int w = tid >> 6;
    const int wm = w >> 2, wn = w & 3;
    const int q = lane >> 4, cl = lane & 15;
    const int nblk = N >> 8;
    const int cpx = (int)gridDim.x >> 3;
    const int logical = ((int)blockIdx.x & 7) * cpx + ((int)blockIdx.x >> 3);
    const int mb = logical / nblk, nb = logical % nblk;

    f32x4 acc[8][4] = {};
    f16x8 af[4][2], bfp[2][2][2];
    const int ITERS = (K >> 6) / 2;

    SA(0, 0, 0); SBm(0, 0, 0); SBm(0, 1, 0); SA(0, 1, 0);
    SA(1, 0, 1); SBm(1, 0, 1);
    VM8;
    SB0; __builtin_amdgcn_s_barrier(); SB0;

#pragma unroll 1
    for (int i = 0; i < ITERS - 1; ++i) {
        const int k2 = 2 * i;
        PH(0, 0, 0, true,  true,  SA(1, 1, k2 + 1),  VM8)   // p1
        PH(0, 0, 1, false, true,  SBm(1, 1, k2 + 1), VM8)   // p2
        PH(0, 1, 0, true,  false, SA(0, 0, k2 + 2),  VMN)   // p3
        PH(0, 1, 1, false, false, SBm(0, 0, k2 + 2), VM8)   // p4
        PH(1, 0, 0, true,  true,  SBm(0, 1, k2 + 2), VM6)   // p5
        PH(1, 0, 1, false, true,  SA(0, 1, k2 + 2),  VMN)   // p6
        PH(1, 1, 0, true,  false, SA(1, 0, k2 + 3),  VMN)   // p7
        PH(1, 1, 1, false, false, SBm(1, 0, k2 + 3), VM8)   // p8
    }
    {
        const int kl = 2 * ITERS - 1;
        PH(0, 0, 0, true,  true,  SA(1, 1, kl),  VM8)
        PH(0, 0, 1, false, true,  SBm(1, 1, kl), VM8)
        PH(0, 1, 0, true,  false, VMN,           VMN)
        PH(0, 1, 1, false, false, VMN,           VM4)
        PH(1, 0, 0, true,  true,  VMN,           VM0)
        PH(1, 0, 1, false, true,  VMN,           VMN)
        PH(1, 1, 0, true,  false, VMN,           VMN)
        PH(1, 1, 1, false, false, VMN,           VMN)
    }

    // C epilogue (+bias)
#pragma unroll
    for (int mt7 = 0; mt7 < 8; ++mt7) {
#pragma unroll
        for (int nt4 = 0; nt4 < 4; ++nt4) {
            int row0 = mb * 256 + (mt7 >> 2) * 128 + wm * 64 + (mt7 & 3) * 16 + q * 4;
            int col = nb * 256 + (nt4 >> 1) * 128 + wn * 32 + (nt4 & 1) * 16 + cl;
            float bv = bias[col];
#pragma unroll
            for (int r = 0; r < 4; ++r) {
                float v = acc[mt7][nt4][r] + bv;
                if (OUT_F16)
                    ((f16*)C_)[(size_t)(row0 + r) * N + col] = (f16)v;
                else
                    ((float*)C_)[(size_t)(row0 + r) * N + col] = v;
            }
        }
    }

    if (COLSUM) {
        float cs[4];
#pragma unroll
        for (int nt4 = 0; nt4 < 4; ++nt4) {
            int col = nb * 256 + (nt4 >> 1) * 128 + wn * 32 + (nt4 & 1) * 16 + cl;
            float s = 32.f * bias[col];
#pragma unroll
            for (int mt7 = 0; mt7 < 8; ++mt7)
#pragma unroll
                for (int r = 0; r < 4; ++r) s += acc[mt7][nt4][r];
            s += __shfl_xor(s, 16);
            s += __shfl_xor(s, 32);
            cs[nt4] = s;
        }
        float* S = (float*)Ad;
        __syncthreads();
        if (q == 0) {
#pragma unroll
            for (int nt4 = 0; nt4 < 4; ++nt4) S[w * 64 + nt4 * 16 + cl] = cs[nt4];
        }
        __syncthreads();
        if (tid < 256) {
            int col = tid;
            int quad = col >> 7, ciq = col & 127;
            int wn2 = ciq >> 5, sub = (ciq >> 4) & 1, cll = col & 15;
            int idx = wn2 * 64 + (quad * 2 + sub) * 16 + cll;
            colsum[(size_t)mb * N + nb * 256 + col] = S[idx] + S[256 + idx];
        }
    }
}

// ---------------- router (reads fused colsum; scale 1/256) ----------------
__global__ __launch_bounds__(64) void router_kernel(const float* __restrict__ colsum,
                                                    const float* __restrict__ emb,
                                                    float* __restrict__ ew) {
    const int t = blockIdx.x;
    const int bn = t >> 3, h = t & 7;
    const int lane = threadIdx.x;
    float acc = 0.f;
    const float* p = colsum + (size_t)bn * 1024 + h * 128;
    if (lane < 16) {
        const float sc = 1.f / 256.f;
        for (int d = 0; d < 128; ++d)
            acc = fmaf(p[d] * sc, emb[d * 16 + lane], acc);
    }
    float m = acc;
#pragma unroll
    for (int o = 8; o; o >>= 1) m = fmaxf(m, __shfl_xor(m, o));
    float pr = __expf(acc - m);
    float s = pr;
#pragma unroll
    for (int o = 8; o; o >>= 1) s += __shfl_xor(s, o);
    if (lane < 16) ew[t * 16 + lane] = pr / s;
}

// ---------------- expert mixture v3: SGPR weights, no LDS ----------------
__global__ __launch_bounds__(256) void mix_kernel(const float* __restrict__ ew,
                                                  const float* __restrict__ FL,
                                                  const float* __restrict__ SL,
                                                  f16* __restrict__ m1h,
                                                  f16* __restrict__ m2h) {
    const int bid = blockIdx.x;
    const int which = bid >> 10;
    const int tg = (bid >> 6) & 15;
    const int chunk = bid & 63;
    const float* src = which ? SL : FL;
    f16* dst = which ? m2h : m1h;
    const int tid = threadIdx.x;
    const int e0 = chunk * 1024 + tid * 4;

    f32x4 fl[16];
#pragma unroll
    for (int e = 0; e < 16; ++e)
        fl[e] = *(const f32x4*)(src + (size_t)e * 65536 + e0);

    const float* wbase = ew + (size_t)tg * 32 * 16;
    float wc[16];
#pragma unroll
    for (int e = 0; e < 16; ++e) wc[e] = wbase[e];

#pragma unroll 1
    for (int tt = 0; tt < 32; ++tt) {
        float wn2[16];
        if (tt < 31) {
#pragma unroll
            for (int e = 0; e < 16; ++e) wn2[e] = wbase[(tt + 1) * 16 + e];
        }
        f32x4 a = {0.f, 0.f, 0.f, 0.f};
#pragma unroll
        for (int e = 0; e < 16; ++e) {
            a[0] = fmaf(wc[e], fl[e][0], a[0]);
            a[1] = fmaf(wc[e], fl[e][1], a[1]);
            a[2] = fmaf(wc[e], fl[e][2], a[2]);
            a[3] = fmaf(wc[e], fl[e][3], a[3]);
        }
        f16x4 h;
        h[0] = (f16)a[0]; h[1] = (f16)a[1]; h[2] = (f16)a[2]; h[3] = (f16)a[3];
        *(f16x4*)(dst + (size_t)(tg * 32 + tt) * 65536 + e0) = h;
        if (tt < 31) {
#pragma unroll
            for (int e = 0; e < 16; ++e) wc[e] = wn2[e];
        }
    }
}

// ============ MLP v5 (plateau best: ~50us) ============
__device__ __forceinline__ void stage_m1c(const f16* m1c, f16* dst, int tid) {
#pragma unroll
    for (int j = 0; j < 4; ++j) {
        int idx = j * 256 + tid;
        int row = idx >> 4, g = idx & 15;
        glds16(m1c + (size_t)row * 128 + (g ^ (row & 7)) * 8, dst + (idx & ~63) * 8);
    }
}
__device__ __forceinline__ void stage_m2c(const f16* m2c, f16* dst, int tid) {
#pragma unroll
    for (int j = 0; j < 4; ++j) {
        int idx = j * 256 + tid;
        int row = idx >> 3, g = idx & 7;
        glds16(m2c + (size_t)row * 512 + (g ^ (row & 7)) * 8, dst + (idx & ~63) * 8);
    }
}

__global__ __launch_bounds__(256) void mlp_kernel(const f16* __restrict__ Xg,
                                                  const f16* __restrict__ m1h,
                                                  const f16* __restrict__ m2h,
                                                  f16* __restrict__ Yg) {
    __shared__ f16 Ws[128 * 64];
    __shared__ f16 Hs[128 * 64];
    const int cpx = (int)gridDim.x >> 3;
    const int logical = ((int)blockIdx.x & 7) * cpx + ((int)blockIdx.x >> 3);
    const int t = logical >> 1, lh = logical & 1;
    const int n = (t >> 3) & 15;
    const int tm = (n > 0) ? (t - 8) : t;
    const int tid = threadIdx.x;
    const int lane = tid & 63, w = tid >> 6;
    const int q = lane >> 4, cl = lane & 15;
    const int l0 = w * 32;

    const f16* Xsrc = Xg + (size_t)t * 32768 + lh * 16384;
    const f16* m1b = m1h + (size_t)tm * 65536;
    const f16* m2b = m2h + (size_t)tm * 65536;

    stage_m1c(m1b, Ws, tid);
    f16x8 xf[2][4];
#pragma unroll
    for (int lt = 0; lt < 2; ++lt) {
        int l = l0 + lt * 16 + cl;
#pragma unroll
        for (int ks = 0; ks < 4; ++ks)
            xf[lt][ks] = *(const f16x8*)(Xsrc + (size_t)l * 128 + ks * 32 + q * 8);
    }
    __syncthreads();

    f32x4 acc2[2][8] = {};
#pragma unroll 1
    for (int ic = 0; ic < 8; ++ic) {
#pragma unroll
        for (int it = 0; it < 4; ++it) {
            f16x8 af2[4];
#pragma unroll
            for (int ks = 0; ks < 4; ++ks) {
                int r = it * 16 + cl;
                af2[ks] = *(const f16x8*)&Ws[r * 128 +
                                             (((ks * 4 + q) ^ (r & 7))) * 8];
            }
            f32x4 a1[2] = {};
#pragma unroll
            for (int ks = 0; ks < 4; ++ks)
#pragma unroll
                for (int lt = 0; lt < 2; ++lt)
                    a1[lt] = MFMA16(af2[ks], xf[lt][ks], a1[lt]);
            int gi = 2 * it + (q >> 1);
            int sub = (q & 1) * 8;
#pragma unroll
            for (int lt = 0; lt < 2; ++lt) {
                int l = l0 + lt * 16 + cl;
                f16x4 hv;
                hv[0] = (f16)fmaxf(a1[lt][0], 0.f);
                hv[1] = (f16)fmaxf(a1[lt][1], 0.f);
                hv[2] = (f16)fmaxf(a1[lt][2], 0.f);
                hv[3] = (f16)fmaxf(a1[lt][3], 0.f);
                *(f16x4*)((char*)Hs + (size_t)l * 128 + ((gi ^ (l & 7)) << 4) + sub) =
                    hv;
            }
        }
        __syncthreads();
        stage_m2c(m2b + ic * 64, Ws, tid);
        __syncthreads();

        f16x8 hf[2][2];
#pragma unroll
        for (int lt = 0; lt < 2; ++lt)
#pragma unroll
            for (int ks = 0; ks < 2; ++ks) {
                int l = l0 + lt * 16 + cl;
                hf[lt][ks] =
                    *(const f16x8*)&Hs[l * 64 + (((ks * 4 + q) ^ (l & 7))) * 8];
            }
#pragma unroll
        for (int nt = 0; nt < 8; ++nt) {
            f16x8 bf2[2];
#pragma unroll
            for (int ks = 0; ks < 2; ++ks) {
                int d = nt * 16 + cl;
                bf2[ks] = *(const f16x8*)&Ws[d * 64 +
                                             (((ks * 4 + q) ^ (d & 7))) * 8];
            }
#pragma unroll
            for (int lt = 0; lt < 2; ++lt)
#pragma unroll
                for (int ks = 0; ks < 2; ++ks)
                    acc2[lt][nt] = MFMA16(hf[lt][ks], bf2[ks], acc2[lt][nt]);
        }
        __syncthreads();
        if (ic < 7) {
            stage_m1c(m1b + (size_t)(ic + 1) * 8192, Ws, tid);
            __syncthreads();
        }
    }

    f16* Yb = Yg + (size_t)t * 32768 + lh * 16384;
#pragma unroll
    for (int lt = 0; lt < 2; ++lt) {
#pragma unroll
        for (int nt = 0; nt < 8; ++nt) {
            int lr = l0 + lt * 16 + q * 4;
            int d = nt * 16 + cl;
#pragma unroll
            for (int r = 0; r < 4; ++r)
                Yb[(size_t)(lr + r) * 128 + d] = (f16)acc2[lt][nt][r];
        }
    }
}

extern "C" void kernel_launch(void* const* d_in, const int* in_sizes, int n_in,
                              void* d_out, int out_size, void* d_ws, size_t ws_size,
                              hipStream_t stream) {
    const float* x    = (const float*)d_in[0];
    const float* W_mh = (const float*)d_in[1];
    const float* b_mh = (const float*)d_in[2];
    const float* W_mg = (const float*)d_in[3];
    const float* b_mg = (const float*)d_in[4];
    const float* emb  = (const float*)d_in[5];
    const float* FL   = (const float*)d_in[6];
    const float* SL   = (const float*)d_in[7];

    char* ws = (char*)d_ws;
    f16*   X1h  = (f16*)(ws + 0);
    f16*   m1h  = (f16*)(ws + 33554432);
    f16*   X0h  = (f16*)(ws + 33554432);   // aliases m1h (dead interval)
    f16*   m2h  = (f16*)(ws + 100663296);
    f16*   Wmhh = (f16*)(ws + 167772160);
    f16*   Wmgh = (f16*)(ws + 169869312);
    float* csum = (float*)(ws + 171966464); // 64 x 1024 f32 = 256KB
    float* ew   = (float*)(ws + 172228608);

    cvt_all_kernel<<<9216, 256, 0, stream>>>(W_mh, W_mg, x, Wmhh, Wmgh, X0h);
    gemm256_kernel<true, true><<<256, 512, 0, stream>>>(X0h, Wmhh, b_mh, X1h,
                                                        csum, 16384, 1024, 1024);
    router_kernel<<<512, 64, 0, stream>>>(csum, emb, ew);
    mix_kernel<<<2048, 256, 0, stream>>>(ew, FL, SL, m1h, m2h);
    mlp_kernel<<<1024, 256, 0, stream>>>(X1h, m1h, m2h, X1h);
    gemm256_kernel<false, false><<<256, 512, 0, stream>>>(X1h, Wmgh, b_mg, d_out,
                                                          nullptr, 16384, 1024, 1024);
}